// Round 2
// baseline (534.498 us; speedup 1.0000x reference)
//
#include <hip/hip_runtime.h>
#include <cstdint>
#include <cstddef>

// EfficientSelfAttention, MI355X. Round 1 (resubmit after broker timeout):
// correct fp32 implementation with the Wv-elimination algebraic rewrite:
//   context = (P_k @ X^T) @ Wv^T + bv  (softmax rows sum to 1)
// 5 heavy kernels, no MFMA yet. Expect ~140 us (K1 VALU-bound, K5 mem-bound).

constexpr int kB  = 2;
constexpr int kC  = 256;
constexpr int kCK = 32;
constexpr int kN  = 65536;           // T*H*W
constexpr int kNCol = kB * kN;       // 131072 columns total

// ---- workspace layout (float element offsets) ----
constexpr size_t OFF_KLOG  = 0;                                   // [B][CK][N]
constexpr size_t OFF_QS    = OFF_KLOG  + (size_t)kB * kCK * kN;   // [B][CK][N]
constexpr size_t OFF_WKT   = OFF_QS    + (size_t)kB * kCK * kN;   // [C][CK]
constexpr size_t OFF_WQT   = OFF_WKT   + (size_t)kC * kCK;        // [C][CK]
constexpr size_t OFF_WVT   = OFF_WQT   + (size_t)kC * kCK;        // [C][C]
constexpr size_t OFF_PMAX  = OFF_WVT   + (size_t)kC * kC;         // [2048][CK]
constexpr size_t OFF_PSUM  = OFF_PMAX  + (size_t)2048 * kCK;      // [2048][CK]
constexpr size_t OFF_ROWM  = OFF_PSUM  + (size_t)2048 * kCK;      // [B][CK]
constexpr size_t OFF_RINV  = OFF_ROWM  + (size_t)kB * kCK;        // [B][CK]
constexpr size_t OFF_MPART = OFF_RINV  + (size_t)kB * kCK;        // [512][CK][C]
constexpr size_t OFF_MG    = OFF_MPART + (size_t)512 * kCK * kC;  // [B][CK][C]
constexpr size_t OFF_CTXT  = OFF_MG    + (size_t)kB * kCK * kC;   // [B][C][CK]
constexpr size_t WS_FLOATS = OFF_CTXT  + (size_t)kB * kC * kCK;   // ~12.83M floats (~49 MB)

// ---------------------------------------------------------------------------
// K0: transpose the weight matrices so K1/K4b get wave-uniform contiguous
// rows -> scalar s_load_dwordx16 in the hot loops.
__global__ void k0_prep(const float* __restrict__ Wq, const float* __restrict__ Wk,
                        const float* __restrict__ Wv, float* __restrict__ WqT,
                        float* __restrict__ WkT, float* __restrict__ WvT) {
    int c = threadIdx.x;  // 256 threads, one per channel c
    for (int d = 0; d < kCK; ++d) {
        WkT[c * kCK + d] = Wk[d * kC + c];
        WqT[c * kCK + d] = Wq[d * kC + c];
    }
    for (int e = 0; e < kC; ++e) {
        WvT[c * kC + e] = Wv[e * kC + c];   // WvT[c][e] = Wv[e][c]
    }
}

// ---------------------------------------------------------------------------
// K1: per column n: klog = WkT^T x + bk (store), q = softmax_d(WqT^T x + bq)
// (store), plus per-wave key-softmax partials (max, sum-exp).
__global__ __launch_bounds__(256) void k1_proj(
    const float* __restrict__ x,
    const float* __restrict__ WqT, const float* __restrict__ bq,
    const float* __restrict__ WkT, const float* __restrict__ bk,
    float* __restrict__ klog, float* __restrict__ qs,
    float* __restrict__ pmax, float* __restrict__ psum) {
    int col = blockIdx.x * 256 + threadIdx.x;
    int b = col >> 16;
    int n = col & (kN - 1);
    const float* xp = x + (size_t)b * kC * kN + n;

    float ka[kCK], qa[kCK];
#pragma unroll
    for (int d = 0; d < kCK; ++d) { ka[d] = bk[d]; qa[d] = bq[d]; }

    for (int c = 0; c < kC; ++c) {
        float xv = xp[(size_t)c * kN];
        const float* wkc = WkT + c * kCK;   // uniform -> scalar loads
        const float* wqc = WqT + c * kCK;
#pragma unroll
        for (int d = 0; d < kCK; ++d) {
            ka[d] = fmaf(wkc[d], xv, ka[d]);
            qa[d] = fmaf(wqc[d], xv, qa[d]);
        }
    }

    // store klog
    float* kp = klog + (size_t)b * kCK * kN + n;
#pragma unroll
    for (int d = 0; d < kCK; ++d) kp[(size_t)d * kN] = ka[d];

    // q softmax over d (local) and store
    float qm = qa[0];
#pragma unroll
    for (int d = 1; d < kCK; ++d) qm = fmaxf(qm, qa[d]);
    float qsum = 0.f;
#pragma unroll
    for (int d = 0; d < kCK; ++d) { qa[d] = __expf(qa[d] - qm); qsum += qa[d]; }
    float qi = 1.0f / qsum;
    float* qp = qs + (size_t)b * kCK * kN + n;
#pragma unroll
    for (int d = 0; d < kCK; ++d) qp[(size_t)d * kN] = qa[d] * qi;

    // per-wave key stats (softmax is over n, global -> two-stage)
    int wv = col >> 6;           // global wave id, 0..2047
    int lane = threadIdx.x & 63;
#pragma unroll
    for (int d = 0; d < kCK; ++d) {
        float m = ka[d];
        for (int o = 32; o > 0; o >>= 1) m = fmaxf(m, __shfl_xor(m, o));
        float e = __expf(ka[d] - m);
        for (int o = 32; o > 0; o >>= 1) e += __shfl_xor(e, o);
        if (lane == 0) { pmax[wv * kCK + d] = m; psum[wv * kCK + d] = e; }
    }
}

// ---------------------------------------------------------------------------
// K2: combine 1024 wave-partials per batch -> rowm[b][d], rowinv[b][d].
__global__ __launch_bounds__(1024) void k2_stats(
    const float* __restrict__ pmax, const float* __restrict__ psum,
    float* __restrict__ rowm, float* __restrict__ rowinv) {
    __shared__ float sm[16][64];
    __shared__ float ss[16][64];
    int t = threadIdx.x;
    int bd = t & 63;          // (b,d) pair
    int seg = t >> 6;         // 16 segments of 64 waves each
    int b = bd >> 5, d = bd & 31;
    int j0 = b * 1024 + seg * 64;

    float m = -1e30f;
    for (int j = 0; j < 64; ++j) m = fmaxf(m, pmax[(size_t)(j0 + j) * kCK + d]);
    sm[seg][bd] = m;
    __syncthreads();
    if (t < 64) {
        float mm = -1e30f;
        for (int s = 0; s < 16; ++s) mm = fmaxf(mm, sm[s][t]);
        sm[0][t] = mm;
    }
    __syncthreads();
    float M = sm[0][bd];
    float s0 = 0.f, s1 = 0.f;
    for (int j = 0; j < 64; j += 2) {
        size_t i0 = (size_t)(j0 + j) * kCK + d;
        size_t i1 = (size_t)(j0 + j + 1) * kCK + d;
        s0 += psum[i0] * __expf(pmax[i0] - M);
        s1 += psum[i1] * __expf(pmax[i1] - M);
    }
    ss[seg][bd] = s0 + s1;
    __syncthreads();
    if (t < 64) {
        float S = 0.f;
        for (int s = 0; s < 16; ++s) S += ss[s][t];
        rowm[t] = sm[0][t];
        rowinv[t] = 1.0f / S;
    }
}

// ---------------------------------------------------------------------------
// K3: M[d,c] = sum_n p_k[d,n] x[c,n], per-block partials.
// Block: 256 threads, register tile 4d x 8c, LDS-staged x[256][64] chunks.
__global__ __launch_bounds__(256) void k3_M(
    const float* __restrict__ x, const float* __restrict__ klog,
    const float* __restrict__ rowm, const float* __restrict__ rowinv,
    float* __restrict__ Mpart) {
    __shared__ float lx[kC][65];      // 256*65*4 = 66.6 KB, +1 pad: stride 65%32=1
    __shared__ float pk[64][33];      // [col][d], stride 33: (33c+d)%32=(c+d)%32

    int t = threadIdx.x;
    int bid = blockIdx.x;             // 0..511; 0..255 -> batch 0
    int b = bid >> 8;
    int jb = bid & 255;               // block index within batch
    int d0 = (t & 7) * 4;
    int c0 = (t >> 3) * 8;
    int lane = t & 63, w = t >> 6;

    float acc[4][8];
#pragma unroll
    for (int i = 0; i < 4; ++i)
#pragma unroll
        for (int j = 0; j < 8; ++j) acc[i][j] = 0.f;

    for (int ch = 0; ch < 4; ++ch) {
        int n0 = jb * 256 + ch * 64;  // 64-column chunk within batch b
        __syncthreads();
        // stage x chunk: wave w loads channel c = i*4+w, cols n0+lane
        {
            const float* xb = x + (size_t)b * kC * kN + n0 + lane;
#pragma unroll 8
            for (int i = 0; i < 64; ++i) {
                int c = i * 4 + w;
                lx[c][lane] = xb[(size_t)c * kN];
            }
            // stage p_k: 2048 entries, coalesced read, conflict-free write
            const float* kb = klog + (size_t)b * kCK * kN + n0;
#pragma unroll
            for (int j = 0; j < 8; ++j) {
                int idx = j * 256 + t;
                int dd = idx >> 6;    // 0..31 (uniform per wave)
                int cc = idx & 63;
                float v = __expf(kb[(size_t)dd * kN + cc] - rowm[b * kCK + dd]) *
                          rowinv[b * kCK + dd];
                pk[cc][dd] = v;
            }
        }
        __syncthreads();
#pragma unroll 4
        for (int col = 0; col < 64; ++col) {
            float p0 = pk[col][d0 + 0];
            float p1 = pk[col][d0 + 1];
            float p2 = pk[col][d0 + 2];
            float p3 = pk[col][d0 + 3];
#pragma unroll
            for (int i = 0; i < 8; ++i) {
                float xv = lx[c0 + i][col];
                acc[0][i] = fmaf(p0, xv, acc[0][i]);
                acc[1][i] = fmaf(p1, xv, acc[1][i]);
                acc[2][i] = fmaf(p2, xv, acc[2][i]);
                acc[3][i] = fmaf(p3, xv, acc[3][i]);
            }
        }
    }
    float* mp = Mpart + (size_t)bid * kCK * kC;
#pragma unroll
    for (int i = 0; i < 4; ++i)
#pragma unroll
        for (int j = 0; j < 8; ++j)
            mp[(d0 + i) * kC + c0 + j] = acc[i][j];
}

// ---------------------------------------------------------------------------
// K4a: reduce 256 block-partials per batch -> Mg[b][d][c].
__global__ __launch_bounds__(256) void k4a_reduce(
    const float* __restrict__ Mpart, float* __restrict__ Mg) {
    int bid = blockIdx.x;             // 64 blocks
    int b = bid >> 5, seg = bid & 31;
    int idx = seg * 256 + threadIdx.x;  // 0..8191
    const float* p = Mpart + (size_t)b * 256 * (kCK * kC) + idx;
    float s0 = 0.f, s1 = 0.f, s2 = 0.f, s3 = 0.f;
    for (int j = 0; j < 256; j += 4) {
        s0 += p[(size_t)(j + 0) * (kCK * kC)];
        s1 += p[(size_t)(j + 1) * (kCK * kC)];
        s2 += p[(size_t)(j + 2) * (kCK * kC)];
        s3 += p[(size_t)(j + 3) * (kCK * kC)];
    }
    Mg[(size_t)b * kCK * kC + idx] = (s0 + s1) + (s2 + s3);
}

// K4b: ctxT[b][e][d] = bv[e] + sum_c Mg[b][d][c] * Wv[e][c]
__global__ __launch_bounds__(256) void k4b_ctx(
    const float* __restrict__ Mg, const float* __restrict__ WvT,
    const float* __restrict__ bv, float* __restrict__ ctxT) {
    int bid = blockIdx.x;             // 64 blocks: b = bid>>5, d = bid&31
    int b = bid >> 5, d = bid & 31;
    int e = threadIdx.x;
    const float* mp = Mg + (size_t)b * kCK * kC + d * kC;  // uniform -> s_load
    float a0 = bv[e], a1 = 0.f, a2 = 0.f, a3 = 0.f;
    for (int c = 0; c < kC; c += 4) {
        a0 = fmaf(mp[c + 0], WvT[(size_t)(c + 0) * kC + e], a0);
        a1 = fmaf(mp[c + 1], WvT[(size_t)(c + 1) * kC + e], a1);
        a2 = fmaf(mp[c + 2], WvT[(size_t)(c + 2) * kC + e], a2);
        a3 = fmaf(mp[c + 3], WvT[(size_t)(c + 3) * kC + e], a3);
    }
    ctxT[((size_t)b * kC + e) * kCK + d] = (a0 + a1) + (a2 + a3);
}

// ---------------------------------------------------------------------------
// K5: out[e,n] = gamma * sum_d ctxT[e][d]*q[d,n] + x[e,n]
__global__ __launch_bounds__(256) void k5_out(
    const float* __restrict__ x, const float* __restrict__ qs,
    const float* __restrict__ ctxT, const float* __restrict__ gamma,
    float* __restrict__ out) {
    int col = blockIdx.x * 256 + threadIdx.x;
    int b = col >> 16;
    int n = col & (kN - 1);
    int bu = __builtin_amdgcn_readfirstlane(b);  // block never spans batches

    const float* qp = qs + (size_t)bu * kCK * kN + n;
    float q[kCK];
#pragma unroll
    for (int d = 0; d < kCK; ++d) q[d] = qp[(size_t)d * kN];

    const float* cp = ctxT + (size_t)bu * kC * kCK;  // uniform -> s_load
    const float* xp = x + (size_t)bu * kC * kN + n;
    float* op = out + (size_t)bu * kC * kN + n;
    float g = gamma[0];

#pragma unroll 4
    for (int e = 0; e < kC; ++e) {
        const float* ce = cp + e * kCK;
        float a0 = 0.f, a1 = 0.f, a2 = 0.f, a3 = 0.f;
#pragma unroll
        for (int d = 0; d < kCK; d += 4) {
            a0 = fmaf(ce[d + 0], q[d + 0], a0);
            a1 = fmaf(ce[d + 1], q[d + 1], a1);
            a2 = fmaf(ce[d + 2], q[d + 2], a2);
            a3 = fmaf(ce[d + 3], q[d + 3], a3);
        }
        float att = (a0 + a1) + (a2 + a3);
        op[(size_t)e * kN] = fmaf(g, att, xp[(size_t)e * kN]);
    }
}

// ---------------------------------------------------------------------------
extern "C" void kernel_launch(void* const* d_in, const int* in_sizes, int n_in,
                              void* d_out, int out_size, void* d_ws, size_t ws_size,
                              hipStream_t stream) {
    const float* x     = (const float*)d_in[0];
    const float* Wq    = (const float*)d_in[1];
    const float* bq    = (const float*)d_in[2];
    const float* Wk    = (const float*)d_in[3];
    const float* bk    = (const float*)d_in[4];
    const float* Wv    = (const float*)d_in[5];
    const float* bv    = (const float*)d_in[6];
    const float* gamma = (const float*)d_in[7];
    float* out = (float*)d_out;
    float* ws  = (float*)d_ws;

    float* klog  = ws + OFF_KLOG;
    float* qsbuf = ws + OFF_QS;
    float* WkT   = ws + OFF_WKT;
    float* WqT   = ws + OFF_WQT;
    float* WvT   = ws + OFF_WVT;
    float* pmax  = ws + OFF_PMAX;
    float* psum  = ws + OFF_PSUM;
    float* rowm  = ws + OFF_ROWM;
    float* rinv  = ws + OFF_RINV;
    float* Mpart = ws + OFF_MPART;
    float* Mg    = ws + OFF_MG;
    float* ctxT  = ws + OFF_CTXT;

    k0_prep<<<1, 256, 0, stream>>>(Wq, Wk, Wv, WqT, WkT, WvT);
    k1_proj<<<kNCol / 256, 256, 0, stream>>>(x, WqT, bq, WkT, bk,
                                             klog, qsbuf, pmax, psum);
    k2_stats<<<1, 1024, 0, stream>>>(pmax, psum, rowm, rinv);
    k3_M<<<512, 256, 0, stream>>>(x, klog, rowm, rinv, Mpart);
    k4a_reduce<<<64, 256, 0, stream>>>(Mpart, Mg);
    k4b_ctx<<<64, 256, 0, stream>>>(Mg, WvT, bv, ctxT);
    k5_out<<<kNCol / 256, 256, 0, stream>>>(x, qsbuf, ctxT, gamma, out);
}

// Round 4
// 371.106 us; speedup vs baseline: 1.4403x; 1.4403x over previous
//
#include <hip/hip_runtime.h>
#include <hip/hip_bf16.h>
#include <cstdint>
#include <cstddef>

// EfficientSelfAttention, MI355X. Round 3 resubmit (broker timeout; kernel
// unchanged): MFMA for both big GEMM passes.
//   A: klog/qsoft projections  (W in regs, X bf16-staged in LDS)
//   C: M[d,c] = sum_n pk[d,n] x[c,n]  (pk frags in regs from klog, X in LDS)
// Wv-elimination: context = (Pk @ X^T) @ Wv^T + bv.
// R2 lesson: 64 fp32 accumulators/thread -> VGPR-starved, latency-bound
// (VALUBusy 25%, 126us). MFMA accs live in the unified VGPR/AGPR file.

constexpr int kB  = 2;
constexpr int kC  = 256;
constexpr int kCK = 32;
constexpr int kN  = 65536;           // T*H*W
constexpr int kNCol = kB * kN;

typedef __attribute__((ext_vector_type(8))) short bf8;   // 8 bf16 (4 VGPR)
typedef __attribute__((ext_vector_type(4))) float f4;    // MFMA C/D frag

// ---- workspace layout (float element offsets) ----
constexpr size_t OFF_KLOG  = 0;                           // [B][CK][N] f32
constexpr size_t OFF_QS    = OFF_KLOG  + 4194304;         // [B][CK][N] f32
constexpr size_t OFF_WPACK = OFF_QS    + 4194304;         // [64][256] bf16 (8192 f)
constexpr size_t OFF_BIAS  = OFF_WPACK + 8192;            // [64] f32 (bk|bq)
constexpr size_t OFF_WVT   = OFF_BIAS  + 64;              // [256][256] f32
constexpr size_t OFF_PMAX  = OFF_WVT   + 65536;           // [1024][32]
constexpr size_t OFF_PSUM  = OFF_PMAX  + 32768;           // [1024][32]
constexpr size_t OFF_ROWM  = OFF_PSUM  + 32768;           // [64]
constexpr size_t OFF_RINV  = OFF_ROWM  + 64;              // [64]
constexpr size_t OFF_MG    = OFF_RINV  + 64;              // [B][32][256]
constexpr size_t OFF_CTXT  = OFF_MG    + 16384;           // [B][256][32]
constexpr size_t OFF_MPART = OFF_CTXT  + 16384;           // [512][32][256]
// total = OFF_MPART + 4194304 = 12,755,136 floats (~48.7 MiB)

static __device__ inline short f2bf(float a) {
    union { __hip_bfloat16 h; short s; } u; u.h = __float2bfloat16(a); return u.s;
}
static __device__ inline unsigned int pack2(float a, float b) {
    union { __hip_bfloat162 h2; unsigned int u; } u;
    u.h2 = __float22bfloat162_rn(float2{a, b});
    return u.u;
}
static __device__ inline bf8 mk_pk(f4 u, f4 v, float rm) {
    bf8 r;
    r[0] = f2bf(__expf(u[0] - rm)); r[1] = f2bf(__expf(u[1] - rm));
    r[2] = f2bf(__expf(u[2] - rm)); r[3] = f2bf(__expf(u[3] - rm));
    r[4] = f2bf(__expf(v[0] - rm)); r[5] = f2bf(__expf(v[1] - rm));
    r[6] = f2bf(__expf(v[2] - rm)); r[7] = f2bf(__expf(v[3] - rm));
    return r;
}

// ---------------------------------------------------------------------------
// K0: pack Wk|Wq -> bf16 Wpack[64][256]; bias_pack; WvT transpose.
__global__ __launch_bounds__(256) void k0_prep(
    const float* __restrict__ Wq, const float* __restrict__ Wk,
    const float* __restrict__ Wv, const float* __restrict__ bq,
    const float* __restrict__ bk, short* __restrict__ wpack,
    float* __restrict__ biasp, float* __restrict__ WvT) {
    int id = blockIdx.x * 256 + threadIdx.x;     // 0..16383
    {   // Wpack
        int d = id >> 8, c = id & 255;
        float v = (d < 32) ? Wk[d * kC + c] : Wq[(d - 32) * kC + c];
        wpack[d * kC + c] = f2bf(v);
    }
#pragma unroll
    for (int j = 0; j < 4; ++j) {                // WvT[c][e] = Wv[e][c]
        int k = id * 4 + j;
        int c = k >> 8, e = k & 255;
        WvT[(size_t)c * kC + e] = Wv[(size_t)e * kC + c];
    }
    if (id < 64) biasp[id] = (id < 32) ? bk[id] : bq[id - 32];
}

// ---------------------------------------------------------------------------
// Pass A: D[64][N] = Wpack @ X  via mfma_f32_16x16x32_bf16.
// Block = 128 n-cols, 4 waves; wave w owns d-tile w (rows w*16..w*16+15),
// all 8 n-tiles. LDS X-chunk [128 n][32 c] bf16, row stride 40 bf16 = 80B
// (80/16 odd -> 16B-slot index (5*row+q)&7 uniform -> conflict-free b128).
// Fragment maps (guide m89/m92): A lane l: row=l&15, k=(l>>4)*8+j (contig);
// B lane l: col=l&15, k=(l>>4)*8+j; D lane l: col=l&15, row=(l>>4)*4+r.
__global__ __launch_bounds__(256, 4) void pa_proj(
    const float* __restrict__ x, const float* __restrict__ wpack_f,
    const float* __restrict__ biasp,
    float* __restrict__ klog, float* __restrict__ qs,
    float* __restrict__ pmax, float* __restrict__ psum) {
    __shared__ __align__(16) unsigned int lds[128 * 20];   // 10240 B
    __shared__ float qex[2][8][16];

    const int t = threadIdx.x;
    const int bid = blockIdx.x;                  // 1024
    const int b = bid >> 9;
    const int n0 = (bid & 511) * 128;
    const int w = t >> 6, l = t & 63;
    const int l15 = l & 15, q = l >> 4;

    // A fragments for all 8 k-chunks (W rows w*16..+15) -> 32 VGPR
    const short* wp = (const short*)wpack_f;
    bf8 afrag[8];
#pragma unroll
    for (int ck = 0; ck < 8; ++ck)
        afrag[ck] = *reinterpret_cast<const bf8*>(
            wp + (w * 16 + l15) * 256 + ck * 32 + q * 8);

    f4 acc[8];
#pragma unroll
    for (int nt = 0; nt < 8; ++nt) acc[nt] = (f4)0.f;

    const int nl = t & 127;                      // staged column
    const int chh = (t >> 7) * 16;               // c-half base (0 or 16)
    const float* xb = x + (size_t)b * kC * kN + n0 + nl;

    float pre[16];
    // prologue: stage chunk 0
#pragma unroll
    for (int j = 0; j < 8; ++j) {
        pre[2 * j]     = xb[(size_t)(chh + 2 * j) * kN];
        pre[2 * j + 1] = xb[(size_t)(chh + 2 * j + 1) * kN];
    }
#pragma unroll
    for (int j = 0; j < 8; ++j)
        lds[nl * 20 + ((chh >> 1) + j)] = pack2(pre[2 * j], pre[2 * j + 1]);
    __syncthreads();

    for (int ck = 0; ck < 8; ++ck) {
        if (ck < 7) {                            // T14: issue next chunk early
            const float* xc = xb + (size_t)(ck + 1) * 32 * kN;
#pragma unroll
            for (int j = 0; j < 8; ++j) {
                pre[2 * j]     = xc[(size_t)(chh + 2 * j) * kN];
                pre[2 * j + 1] = xc[(size_t)(chh + 2 * j + 1) * kN];
            }
        }
#pragma unroll
        for (int nt = 0; nt < 8; ++nt) {
            bf8 bfrag = *reinterpret_cast<const bf8*>(
                (const short*)lds + (nt * 16 + l15) * 40 + q * 8);
            acc[nt] = __builtin_amdgcn_mfma_f32_16x16x32_bf16(
                afrag[ck], bfrag, acc[nt], 0, 0, 0);
        }
        __syncthreads();                         // all waves done reading
        if (ck < 7) {
#pragma unroll
            for (int j = 0; j < 8; ++j)
                lds[nl * 20 + ((chh >> 1) + j)] =
                    pack2(pre[2 * j], pre[2 * j + 1]);
            __syncthreads();                     // chunk ready
        }
    }

    // epilogue: add bias; wave 0,1 = k rows 0..31; wave 2,3 = q rows 0..31
    const f4 bias = *reinterpret_cast<const f4*>(biasp + w * 16 + q * 4);
    float v[8][4];
#pragma unroll
    for (int nt = 0; nt < 8; ++nt)
#pragma unroll
        for (int r = 0; r < 4; ++r) v[nt][r] = acc[nt][r] + bias[r];

    if (w < 2) {
        // store klog
        float* kp = klog + (size_t)b * kCK * kN + n0 + l15;
#pragma unroll
        for (int nt = 0; nt < 8; ++nt)
#pragma unroll
            for (int r = 0; r < 4; ++r) {
                int d = w * 16 + q * 4 + r;
                kp[(size_t)d * kN + nt * 16] = v[nt][r];
            }
        // per-(block,row) softmax partials over the 128 cols
#pragma unroll
        for (int r = 0; r < 4; ++r) {
            float m = v[0][r];
#pragma unroll
            for (int nt = 1; nt < 8; ++nt) m = fmaxf(m, v[nt][r]);
            m = fmaxf(m, __shfl_xor(m, 1)); m = fmaxf(m, __shfl_xor(m, 2));
            m = fmaxf(m, __shfl_xor(m, 4)); m = fmaxf(m, __shfl_xor(m, 8));
            float s = 0.f;
#pragma unroll
            for (int nt = 0; nt < 8; ++nt) s += __expf(v[nt][r] - m);
            s += __shfl_xor(s, 1); s += __shfl_xor(s, 2);
            s += __shfl_xor(s, 4); s += __shfl_xor(s, 8);
            if (l15 == 0) {
                int d = w * 16 + q * 4 + r;
                pmax[(size_t)bid * 32 + d] = m;
                psum[(size_t)bid * 32 + d] = s;
            }
        }
    }

    // q softmax over d (32 rows split across waves 2,3) — 3 shared barriers
    float mw[8], e[8][4], sw[8];
    if (w >= 2) {
#pragma unroll
        for (int nt = 0; nt < 8; ++nt) {
            float m = fmaxf(fmaxf(v[nt][0], v[nt][1]), fmaxf(v[nt][2], v[nt][3]));
            m = fmaxf(m, __shfl_xor(m, 16));
            m = fmaxf(m, __shfl_xor(m, 32));
            mw[nt] = m;
            if (q == 0) qex[w - 2][nt][l15] = m;
        }
    }
    __syncthreads();
    if (w >= 2) {
#pragma unroll
        for (int nt = 0; nt < 8; ++nt) {
            float m = fmaxf(mw[nt], qex[3 - w][nt][l15]);
            mw[nt] = m;
            float s = 0.f;
#pragma unroll
            for (int r = 0; r < 4; ++r) { e[nt][r] = __expf(v[nt][r] - m); s += e[nt][r]; }
            s += __shfl_xor(s, 16);
            s += __shfl_xor(s, 32);
            sw[nt] = s;
        }
    }
    __syncthreads();
    if (w >= 2 && q == 0) {
#pragma unroll
        for (int nt = 0; nt < 8; ++nt) qex[w - 2][nt][l15] = sw[nt];
    }
    __syncthreads();
    if (w >= 2) {
        float* qp = qs + (size_t)b * kCK * kN + n0 + l15;
#pragma unroll
        for (int nt = 0; nt < 8; ++nt) {
            float inv = 1.0f / (sw[nt] + qex[3 - w][nt][l15]);
#pragma unroll
            for (int r = 0; r < 4; ++r) {
                int dq = (w - 2) * 16 + q * 4 + r;
                qp[(size_t)dq * kN + nt * 16] = e[nt][r] * inv;
            }
        }
    }
}

// ---------------------------------------------------------------------------
// K2: combine 512 segment-partials per batch -> rowm, rowinv.
__global__ __launch_bounds__(1024) void k2_stats(
    const float* __restrict__ pmax, const float* __restrict__ psum,
    float* __restrict__ rowm, float* __restrict__ rowinv) {
    __shared__ float sm[16][64];
    __shared__ float ss[16][64];
    int t = threadIdx.x;
    int bd = t & 63, seg = t >> 6;
    int b = bd >> 5, d = bd & 31;
    int j0 = b * 512 + seg * 32;

    float m = -1e30f;
    for (int j = 0; j < 32; ++j) m = fmaxf(m, pmax[(size_t)(j0 + j) * 32 + d]);
    sm[seg][bd] = m;
    __syncthreads();
    if (t < 64) {
        float mm = -1e30f;
        for (int s = 0; s < 16; ++s) mm = fmaxf(mm, sm[s][t]);
        sm[0][t] = mm;
    }
    __syncthreads();
    float M = sm[0][bd];
    float s0 = 0.f, s1 = 0.f;
    for (int j = 0; j < 32; j += 2) {
        size_t i0 = (size_t)(j0 + j) * 32 + d;
        size_t i1 = i0 + 32;
        s0 += psum[i0] * __expf(pmax[i0] - M);
        s1 += psum[i1] * __expf(pmax[i1] - M);
    }
    ss[seg][bd] = s0 + s1;
    __syncthreads();
    if (t < 64) {
        float S = 0.f;
        for (int s = 0; s < 16; ++s) S += ss[s][t];
        rowm[t] = sm[0][t];
        rowinv[t] = 1.0f / S;
    }
}

// ---------------------------------------------------------------------------
// Pass C: Mpart[bid] = sum over block's 256 n of exp(klog-rowm)[d,n]*x[c,n].
// A = pk (built in regs from klog, 1/S deferred to k4b), B = x (bf16 LDS,
// [256 c][64 n], stride 72 bf16 = 144B, 144/16 odd -> conflict-free).
// Wave w: c-tiles w*4..w*4+3, both d-tiles. acc = 8 tiles = 32 VGPR.
__global__ __launch_bounds__(256, 2) void pc_M(
    const float* __restrict__ x, const float* __restrict__ klog,
    const float* __restrict__ rowm, float* __restrict__ Mpart) {
    __shared__ __align__(16) unsigned int lds[256 * 36];   // 36864 B

    const int t = threadIdx.x;
    const int bid = blockIdx.x;                  // 512
    const int b = bid >> 8;
    const int n0 = (bid & 255) * 256;
    const int w = t >> 6, l = t & 63;
    const int l15 = l & 15, q = l >> 4;

    const float rm0 = rowm[b * 32 + l15];
    const float rm1 = rowm[b * 32 + 16 + l15];

    f4 acc[4][2];
#pragma unroll
    for (int i = 0; i < 4; ++i) { acc[i][0] = (f4)0.f; acc[i][1] = (f4)0.f; }

    const int np = t & 31;                       // n-pair (n = 2np, 2np+1)
    const int cs = t >> 5;                       // c = cs + 8j
    const float* xb = x + (size_t)b * kC * kN + n0;
    const float* kb = klog + (size_t)b * kCK * kN;

    float2 pre[32];
#pragma unroll
    for (int j = 0; j < 32; ++j)
        pre[j] = *reinterpret_cast<const float2*>(
            xb + (size_t)(cs + 8 * j) * kN + 2 * np);
#pragma unroll
    for (int j = 0; j < 32; ++j)
        lds[(cs + 8 * j) * 36 + np] = pack2(pre[j].x, pre[j].y);
    __syncthreads();

    for (int ch = 0; ch < 4; ++ch) {             // 4 chunks of 64 n
        if (ch < 3) {
            const float* xc = xb + (ch + 1) * 64;
#pragma unroll
            for (int j = 0; j < 32; ++j)
                pre[j] = *reinterpret_cast<const float2*>(
                    xc + (size_t)(cs + 8 * j) * kN + 2 * np);
        }
#pragma unroll
        for (int i = 0; i < 2; ++i) {            // 2 k-steps of 32 n
            const int nwin = n0 + ch * 64 + i * 32;
            const float* kr0 = kb + (size_t)l15 * kN + nwin + q * 8;
            const float* kr1 = kr0 + (size_t)16 * kN;
            f4 u0 = *(const f4*)kr0, u1 = *(const f4*)(kr0 + 4);
            f4 w0 = *(const f4*)kr1, w1 = *(const f4*)(kr1 + 4);
            bf8 a0 = mk_pk(u0, u1, rm0);
            bf8 a1 = mk_pk(w0, w1, rm1);
#pragma unroll
            for (int c4 = 0; c4 < 4; ++c4) {
                int ct = w * 4 + c4;
                bf8 bfr = *reinterpret_cast<const bf8*>(
                    (const short*)lds + (ct * 16 + l15) * 72 + i * 32 + q * 8);
                acc[c4][0] = __builtin_amdgcn_mfma_f32_16x16x32_bf16(
                    a0, bfr, acc[c4][0], 0, 0, 0);
                acc[c4][1] = __builtin_amdgcn_mfma_f32_16x16x32_bf16(
                    a1, bfr, acc[c4][1], 0, 0, 0);
            }
        }
        __syncthreads();
        if (ch < 3) {
#pragma unroll
            for (int j = 0; j < 32; ++j)
                lds[(cs + 8 * j) * 36 + np] = pack2(pre[j].x, pre[j].y);
            __syncthreads();
        }
    }

    float* mp = Mpart + (size_t)bid * (32 * 256);
#pragma unroll
    for (int c4 = 0; c4 < 4; ++c4)
#pragma unroll
        for (int dt = 0; dt < 2; ++dt)
#pragma unroll
            for (int r = 0; r < 4; ++r)
                mp[(dt * 16 + q * 4 + r) * 256 + (w * 4 + c4) * 16 + l15] =
                    acc[c4][dt][r];
}

// ---------------------------------------------------------------------------
// K4a: reduce 256 block-partials per batch -> Mg[b][d][c].
__global__ __launch_bounds__(256) void k4a_reduce(
    const float* __restrict__ Mpart, float* __restrict__ Mg) {
    int bid = blockIdx.x;                        // 64
    int b = bid >> 5, seg = bid & 31;
    int idx = seg * 256 + threadIdx.x;
    const float* p = Mpart + (size_t)b * 256 * 8192 + idx;
    float s0 = 0.f, s1 = 0.f, s2 = 0.f, s3 = 0.f;
    for (int j = 0; j < 256; j += 4) {
        s0 += p[(size_t)(j + 0) * 8192];
        s1 += p[(size_t)(j + 1) * 8192];
        s2 += p[(size_t)(j + 2) * 8192];
        s3 += p[(size_t)(j + 3) * 8192];
    }
    Mg[(size_t)b * 8192 + idx] = (s0 + s1) + (s2 + s3);
}

// K4b: ctxT[b][e][d] = bv[e] + rinv[b][d] * sum_c Mg[b][d][c] * Wv[e][c]
__global__ __launch_bounds__(256) void k4b_ctx(
    const float* __restrict__ Mg, const float* __restrict__ WvT,
    const float* __restrict__ bv, const float* __restrict__ rinv,
    float* __restrict__ ctxT) {
    int bid = blockIdx.x;                        // 64: b = bid>>5, d = bid&31
    int b = bid >> 5, d = bid & 31;
    int e = threadIdx.x;
    const float* mp = Mg + (size_t)b * 8192 + d * 256;   // uniform -> s_load
    float ri = rinv[b * 32 + d];
    float a0 = 0.f, a1 = 0.f, a2 = 0.f, a3 = 0.f;
    for (int c = 0; c < 256; c += 4) {
        a0 = fmaf(mp[c + 0], WvT[(size_t)(c + 0) * kC + e], a0);
        a1 = fmaf(mp[c + 1], WvT[(size_t)(c + 1) * kC + e], a1);
        a2 = fmaf(mp[c + 2], WvT[(size_t)(c + 2) * kC + e], a2);
        a3 = fmaf(mp[c + 3], WvT[(size_t)(c + 3) * kC + e], a3);
    }
    ctxT[((size_t)b * kC + e) * kCK + d] = fmaf(ri, (a0 + a1) + (a2 + a3), bv[e]);
}

// ---------------------------------------------------------------------------
// K5: out[e,n] = gamma * sum_d ctxT[e][d]*q[d,n] + x[e,n].
// Batched 8-wide e-phases -> 8 outstanding x loads per wave.
__global__ __launch_bounds__(256) void k5_out(
    const float* __restrict__ x, const float* __restrict__ qs,
    const float* __restrict__ ctxT, const float* __restrict__ gamma,
    float* __restrict__ out) {
    int col = blockIdx.x * 256 + threadIdx.x;
    int b = col >> 16;
    int n = col & (kN - 1);
    int bu = __builtin_amdgcn_readfirstlane(b);

    const float* qp = qs + (size_t)bu * kCK * kN + n;
    float qv[kCK];
#pragma unroll
    for (int d = 0; d < kCK; ++d) qv[d] = qp[(size_t)d * kN];

    const float* cp = ctxT + (size_t)bu * kC * kCK;      // uniform -> s_load
    const float* xp = x + (size_t)bu * kC * kN + n;
    float* op = out + (size_t)bu * kC * kN + n;
    float g = gamma[0];

    for (int e0 = 0; e0 < kC; e0 += 8) {
        float xv[8];
#pragma unroll
        for (int ee = 0; ee < 8; ++ee) xv[ee] = xp[(size_t)(e0 + ee) * kN];
#pragma unroll
        for (int ee = 0; ee < 8; ++ee) {
            const float* ce = cp + (e0 + ee) * kCK;
            float a0 = 0.f, a1 = 0.f, a2 = 0.f, a3 = 0.f;
#pragma unroll
            for (int d = 0; d < kCK; d += 4) {
                a0 = fmaf(ce[d + 0], qv[d + 0], a0);
                a1 = fmaf(ce[d + 1], qv[d + 1], a1);
                a2 = fmaf(ce[d + 2], qv[d + 2], a2);
                a3 = fmaf(ce[d + 3], qv[d + 3], a3);
            }
            float att = (a0 + a1) + (a2 + a3);
            op[(size_t)(e0 + ee) * kN] = fmaf(g, att, xv[ee]);
        }
    }
}

// ---------------------------------------------------------------------------
extern "C" void kernel_launch(void* const* d_in, const int* in_sizes, int n_in,
                              void* d_out, int out_size, void* d_ws, size_t ws_size,
                              hipStream_t stream) {
    const float* x     = (const float*)d_in[0];
    const float* Wq    = (const float*)d_in[1];
    const float* bq    = (const float*)d_in[2];
    const float* Wk    = (const float*)d_in[3];
    const float* bk    = (const float*)d_in[4];
    const float* Wv    = (const float*)d_in[5];
    const float* bv    = (const float*)d_in[6];
    const float* gamma = (const float*)d_in[7];
    float* out = (float*)d_out;
    float* ws  = (float*)d_ws;

    float* klog  = ws + OFF_KLOG;
    float* qsbuf = ws + OFF_QS;
    float* wpack = ws + OFF_WPACK;
    float* biasp = ws + OFF_BIAS;
    float* WvT   = ws + OFF_WVT;
    float* pmax  = ws + OFF_PMAX;
    float* psum  = ws + OFF_PSUM;
    float* rowm  = ws + OFF_ROWM;
    float* rinv  = ws + OFF_RINV;
    float* Mg    = ws + OFF_MG;
    float* ctxT  = ws + OFF_CTXT;
    float* Mpart = ws + OFF_MPART;

    k0_prep<<<64, 256, 0, stream>>>(Wq, Wk, Wv, bq, bk,
                                    (short*)wpack, biasp, WvT);
    pa_proj<<<1024, 256, 0, stream>>>(x, wpack, biasp, klog, qsbuf, pmax, psum);
    k2_stats<<<1, 1024, 0, stream>>>(pmax, psum, rowm, rinv);
    pc_M<<<512, 256, 0, stream>>>(x, klog, rowm, Mpart);
    k4a_reduce<<<64, 256, 0, stream>>>(Mpart, Mg);
    k4b_ctx<<<64, 256, 0, stream>>>(Mg, WvT, bv, rinv, ctxT);
    k5_out<<<512, 256, 0, stream>>>(x, qsbuf, ctxT, gamma, out);
}

// Round 5
// 345.170 us; speedup vs baseline: 1.5485x; 1.0751x over previous
//
#include <hip/hip_runtime.h>
#include <hip/hip_bf16.h>
#include <cstdint>
#include <cstddef>

// EfficientSelfAttention, MI355X. Round 5:
//  - k5: e-split x4 (grid 2048, 8 blocks/CU) to fix latency-bound 21% occ
//    (R4: 83us @ 2.5 TB/s). qs stored bf16 to offset the x4 re-read.
//  - pc_M: exp/cvt hoisted into streaming k3_pk pass; inner loop pure MFMA.
//  - pa_proj: qs store now bf16.
// Wv-elimination: context = (Pk @ X^T) @ Wv^T + bv.

constexpr int kB  = 2;
constexpr int kC  = 256;
constexpr int kCK = 32;
constexpr int kN  = 65536;           // T*H*W

typedef __attribute__((ext_vector_type(8))) short bf8;   // 8 bf16 (4 VGPR)
typedef __attribute__((ext_vector_type(4))) float f4;    // MFMA C/D frag
typedef __attribute__((ext_vector_type(4))) unsigned int u4;

// ---- workspace layout (float element offsets) ----
constexpr size_t OFF_KLOG  = 0;                           // [B][CK][N] f32
constexpr size_t OFF_QS    = OFF_KLOG  + 4194304;         // [B][CK][N] bf16 (2.1M f)
constexpr size_t OFF_PK    = OFF_QS    + 2097152;         // [B][CK][N] bf16 (2.1M f)
constexpr size_t OFF_WPACK = OFF_PK    + 2097152;         // [64][256] bf16 (8192 f)
constexpr size_t OFF_BIAS  = OFF_WPACK + 8192;            // [64] f32 (bk|bq)
constexpr size_t OFF_WVT   = OFF_BIAS  + 64;              // [256][256] f32
constexpr size_t OFF_PMAX  = OFF_WVT   + 65536;           // [1024][32]
constexpr size_t OFF_PSUM  = OFF_PMAX  + 32768;           // [1024][32]
constexpr size_t OFF_ROWM  = OFF_PSUM  + 32768;           // [64]
constexpr size_t OFF_RINV  = OFF_ROWM  + 64;              // [64]
constexpr size_t OFF_MG    = OFF_RINV  + 64;              // [B][32][256]
constexpr size_t OFF_CTXT  = OFF_MG    + 16384;           // [B][256][32]
constexpr size_t OFF_MPART = OFF_CTXT  + 16384;           // [512][32][256]
// total = OFF_MPART + 4194304 floats (~48.7 MiB) — same budget as R4

static __device__ inline short f2bf(float a) {
    union { __hip_bfloat16 h; short s; } u; u.h = __float2bfloat16(a); return u.s;
}
static __device__ inline float bf2f(short s) {
    union { float f; unsigned int u; } z;
    z.u = ((unsigned int)(unsigned short)s) << 16;
    return z.f;
}
static __device__ inline unsigned int pack2(float a, float b) {
    union { __hip_bfloat162 h2; unsigned int u; } u;
    u.h2 = __float22bfloat162_rn(float2{a, b});
    return u.u;
}

// ---------------------------------------------------------------------------
// K0: pack Wk|Wq -> bf16 Wpack[64][256]; bias_pack; WvT transpose.
__global__ __launch_bounds__(256) void k0_prep(
    const float* __restrict__ Wq, const float* __restrict__ Wk,
    const float* __restrict__ Wv, const float* __restrict__ bq,
    const float* __restrict__ bk, short* __restrict__ wpack,
    float* __restrict__ biasp, float* __restrict__ WvT) {
    int id = blockIdx.x * 256 + threadIdx.x;     // 0..16383
    {   // Wpack
        int d = id >> 8, c = id & 255;
        float v = (d < 32) ? Wk[d * kC + c] : Wq[(d - 32) * kC + c];
        wpack[d * kC + c] = f2bf(v);
    }
#pragma unroll
    for (int j = 0; j < 4; ++j) {                // WvT[c][e] = Wv[e][c]
        int k = id * 4 + j;
        int c = k >> 8, e = k & 255;
        WvT[(size_t)c * kC + e] = Wv[(size_t)e * kC + c];
    }
    if (id < 64) biasp[id] = (id < 32) ? bk[id] : bq[id - 32];
}

// ---------------------------------------------------------------------------
// Pass A: D[64][N] = Wpack @ X  via mfma_f32_16x16x32_bf16.
// Block = 128 n-cols, 4 waves; wave w owns d-tile w, all 8 n-tiles.
// LDS X-chunk [128 n][32 c] bf16, row stride 40 bf16 = 80B (80/16 odd
// -> conflict-free b128). qs now stored bf16.
__global__ __launch_bounds__(256, 4) void pa_proj(
    const float* __restrict__ x, const float* __restrict__ wpack_f,
    const float* __restrict__ biasp,
    float* __restrict__ klog, short* __restrict__ qs,
    float* __restrict__ pmax, float* __restrict__ psum) {
    __shared__ __align__(16) unsigned int lds[128 * 20];   // 10240 B
    __shared__ float qex[2][8][16];

    const int t = threadIdx.x;
    const int bid = blockIdx.x;                  // 1024
    const int b = bid >> 9;
    const int n0 = (bid & 511) * 128;
    const int w = t >> 6, l = t & 63;
    const int l15 = l & 15, q = l >> 4;

    const short* wp = (const short*)wpack_f;
    bf8 afrag[8];
#pragma unroll
    for (int ck = 0; ck < 8; ++ck)
        afrag[ck] = *reinterpret_cast<const bf8*>(
            wp + (w * 16 + l15) * 256 + ck * 32 + q * 8);

    f4 acc[8];
#pragma unroll
    for (int nt = 0; nt < 8; ++nt) acc[nt] = (f4)0.f;

    const int nl = t & 127;
    const int chh = (t >> 7) * 16;
    const float* xb = x + (size_t)b * kC * kN + n0 + nl;

    float pre[16];
#pragma unroll
    for (int j = 0; j < 8; ++j) {
        pre[2 * j]     = xb[(size_t)(chh + 2 * j) * kN];
        pre[2 * j + 1] = xb[(size_t)(chh + 2 * j + 1) * kN];
    }
#pragma unroll
    for (int j = 0; j < 8; ++j)
        lds[nl * 20 + ((chh >> 1) + j)] = pack2(pre[2 * j], pre[2 * j + 1]);
    __syncthreads();

    for (int ck = 0; ck < 8; ++ck) {
        if (ck < 7) {                            // T14: issue next chunk early
            const float* xc = xb + (size_t)(ck + 1) * 32 * kN;
#pragma unroll
            for (int j = 0; j < 8; ++j) {
                pre[2 * j]     = xc[(size_t)(chh + 2 * j) * kN];
                pre[2 * j + 1] = xc[(size_t)(chh + 2 * j + 1) * kN];
            }
        }
#pragma unroll
        for (int nt = 0; nt < 8; ++nt) {
            bf8 bfrag = *reinterpret_cast<const bf8*>(
                (const short*)lds + (nt * 16 + l15) * 40 + q * 8);
            acc[nt] = __builtin_amdgcn_mfma_f32_16x16x32_bf16(
                afrag[ck], bfrag, acc[nt], 0, 0, 0);
        }
        __syncthreads();
        if (ck < 7) {
#pragma unroll
            for (int j = 0; j < 8; ++j)
                lds[nl * 20 + ((chh >> 1) + j)] =
                    pack2(pre[2 * j], pre[2 * j + 1]);
            __syncthreads();
        }
    }

    const f4 bias = *reinterpret_cast<const f4*>(biasp + w * 16 + q * 4);
    float v[8][4];
#pragma unroll
    for (int nt = 0; nt < 8; ++nt)
#pragma unroll
        for (int r = 0; r < 4; ++r) v[nt][r] = acc[nt][r] + bias[r];

    if (w < 2) {
        float* kp = klog + (size_t)b * kCK * kN + n0 + l15;
#pragma unroll
        for (int nt = 0; nt < 8; ++nt)
#pragma unroll
            for (int r = 0; r < 4; ++r) {
                int d = w * 16 + q * 4 + r;
                kp[(size_t)d * kN + nt * 16] = v[nt][r];
            }
#pragma unroll
        for (int r = 0; r < 4; ++r) {
            float m = v[0][r];
#pragma unroll
            for (int nt = 1; nt < 8; ++nt) m = fmaxf(m, v[nt][r]);
            m = fmaxf(m, __shfl_xor(m, 1)); m = fmaxf(m, __shfl_xor(m, 2));
            m = fmaxf(m, __shfl_xor(m, 4)); m = fmaxf(m, __shfl_xor(m, 8));
            float s = 0.f;
#pragma unroll
            for (int nt = 0; nt < 8; ++nt) s += __expf(v[nt][r] - m);
            s += __shfl_xor(s, 1); s += __shfl_xor(s, 2);
            s += __shfl_xor(s, 4); s += __shfl_xor(s, 8);
            if (l15 == 0) {
                int d = w * 16 + q * 4 + r;
                pmax[(size_t)bid * 32 + d] = m;
                psum[(size_t)bid * 32 + d] = s;
            }
        }
    }

    // q softmax over d (32 rows split across waves 2,3)
    float mw[8], e[8][4], sw[8];
    if (w >= 2) {
#pragma unroll
        for (int nt = 0; nt < 8; ++nt) {
            float m = fmaxf(fmaxf(v[nt][0], v[nt][1]), fmaxf(v[nt][2], v[nt][3]));
            m = fmaxf(m, __shfl_xor(m, 16));
            m = fmaxf(m, __shfl_xor(m, 32));
            mw[nt] = m;
            if (q == 0) qex[w - 2][nt][l15] = m;
        }
    }
    __syncthreads();
    if (w >= 2) {
#pragma unroll
        for (int nt = 0; nt < 8; ++nt) {
            float m = fmaxf(mw[nt], qex[3 - w][nt][l15]);
            float s = 0.f;
#pragma unroll
            for (int r = 0; r < 4; ++r) { e[nt][r] = __expf(v[nt][r] - m); s += e[nt][r]; }
            s += __shfl_xor(s, 16);
            s += __shfl_xor(s, 32);
            sw[nt] = s;
        }
    }
    __syncthreads();
    if (w >= 2 && q == 0) {
#pragma unroll
        for (int nt = 0; nt < 8; ++nt) qex[w - 2][nt][l15] = sw[nt];
    }
    __syncthreads();
    if (w >= 2) {
        short* qp = qs + (size_t)b * kCK * kN + n0 + l15;
#pragma unroll
        for (int nt = 0; nt < 8; ++nt) {
            float inv = 1.0f / (sw[nt] + qex[3 - w][nt][l15]);
#pragma unroll
            for (int r = 0; r < 4; ++r) {
                int dq = (w - 2) * 16 + q * 4 + r;
                qp[(size_t)dq * kN + nt * 16] = f2bf(e[nt][r] * inv);
            }
        }
    }
}

// ---------------------------------------------------------------------------
// K2: combine 512 segment-partials per batch -> rowm, rowinv.
__global__ __launch_bounds__(1024) void k2_stats(
    const float* __restrict__ pmax, const float* __restrict__ psum,
    float* __restrict__ rowm, float* __restrict__ rowinv) {
    __shared__ float sm[16][64];
    __shared__ float ss[16][64];
    int t = threadIdx.x;
    int bd = t & 63, seg = t >> 6;
    int b = bd >> 5, d = bd & 31;
    int j0 = b * 512 + seg * 32;

    float m = -1e30f;
    for (int j = 0; j < 32; ++j) m = fmaxf(m, pmax[(size_t)(j0 + j) * 32 + d]);
    sm[seg][bd] = m;
    __syncthreads();
    if (t < 64) {
        float mm = -1e30f;
        for (int s = 0; s < 16; ++s) mm = fmaxf(mm, sm[s][t]);
        sm[0][t] = mm;
    }
    __syncthreads();
    float M = sm[0][bd];
    float s0 = 0.f, s1 = 0.f;
    for (int j = 0; j < 32; j += 2) {
        size_t i0 = (size_t)(j0 + j) * 32 + d;
        size_t i1 = i0 + 32;
        s0 += psum[i0] * __expf(pmax[i0] - M);
        s1 += psum[i1] * __expf(pmax[i1] - M);
    }
    ss[seg][bd] = s0 + s1;
    __syncthreads();
    if (t < 64) {
        float S = 0.f;
        for (int s = 0; s < 16; ++s) S += ss[s][t];
        rowm[t] = sm[0][t];
        rowinv[t] = 1.0f / S;
    }
}

// ---------------------------------------------------------------------------
// K3pk: pk[b][d][n] = bf16(exp(klog - rowm)). Streaming, 8 elems/thread.
__global__ __launch_bounds__(256) void k3_pk(
    const float* __restrict__ klog, const float* __restrict__ rowm,
    short* __restrict__ pk) {
    size_t base = ((size_t)blockIdx.x * 256 + threadIdx.x) * 8;
    int row = (int)(base >> 16);                 // b*32+d (N = 65536)
    float rm = rowm[row];
    f4 u = *reinterpret_cast<const f4*>(klog + base);
    f4 v = *reinterpret_cast<const f4*>(klog + base + 4);
    u4 o;
    o.x = pack2(__expf(u[0] - rm), __expf(u[1] - rm));
    o.y = pack2(__expf(u[2] - rm), __expf(u[3] - rm));
    o.z = pack2(__expf(v[0] - rm), __expf(v[1] - rm));
    o.w = pack2(__expf(v[2] - rm), __expf(v[3] - rm));
    *reinterpret_cast<u4*>(pk + base) = o;
}

// ---------------------------------------------------------------------------
// Pass C: Mpart[bid] = sum over block's 256 n of pk[d,n]*x[c,n].
// A = pk bf16 direct from global (16B/lane contiguous); B = x (bf16 LDS,
// [256 c][64 n], stride 72 bf16 = 144B, 144/16 odd -> conflict-free).
__global__ __launch_bounds__(256, 2) void pc_M(
    const float* __restrict__ x, const short* __restrict__ pk,
    float* __restrict__ Mpart) {
    __shared__ __align__(16) unsigned int lds[256 * 36];   // 36864 B

    const int t = threadIdx.x;
    const int bid = blockIdx.x;                  // 512
    const int b = bid >> 8;
    const int n0 = (bid & 255) * 256;
    const int w = t >> 6, l = t & 63;
    const int l15 = l & 15, q = l >> 4;

    f4 acc[4][2];
#pragma unroll
    for (int i = 0; i < 4; ++i) { acc[i][0] = (f4)0.f; acc[i][1] = (f4)0.f; }

    const int np = t & 31;                       // n-pair (n = 2np, 2np+1)
    const int cs = t >> 5;                       // c = cs + 8j
    const float* xb = x + (size_t)b * kC * kN + n0;
    const short* kb = pk + (size_t)b * kCK * kN;

    float2 pre[32];
#pragma unroll
    for (int j = 0; j < 32; ++j)
        pre[j] = *reinterpret_cast<const float2*>(
            xb + (size_t)(cs + 8 * j) * kN + 2 * np);
#pragma unroll
    for (int j = 0; j < 32; ++j)
        lds[(cs + 8 * j) * 36 + np] = pack2(pre[j].x, pre[j].y);
    __syncthreads();

    for (int ch = 0; ch < 4; ++ch) {             // 4 chunks of 64 n
        if (ch < 3) {
            const float* xc = xb + (ch + 1) * 64;
#pragma unroll
            for (int j = 0; j < 32; ++j)
                pre[j] = *reinterpret_cast<const float2*>(
                    xc + (size_t)(cs + 8 * j) * kN + 2 * np);
        }
#pragma unroll
        for (int i = 0; i < 2; ++i) {            // 2 k-steps of 32 n
            const int nwin = n0 + ch * 64 + i * 32;
            const short* kr0 = kb + (size_t)l15 * kN + nwin + q * 8;
            bf8 a0 = *reinterpret_cast<const bf8*>(kr0);
            bf8 a1 = *reinterpret_cast<const bf8*>(kr0 + (size_t)16 * kN);
#pragma unroll
            for (int c4 = 0; c4 < 4; ++c4) {
                int ct = w * 4 + c4;
                bf8 bfr = *reinterpret_cast<const bf8*>(
                    (const short*)lds + (ct * 16 + l15) * 72 + i * 32 + q * 8);
                acc[c4][0] = __builtin_amdgcn_mfma_f32_16x16x32_bf16(
                    a0, bfr, acc[c4][0], 0, 0, 0);
                acc[c4][1] = __builtin_amdgcn_mfma_f32_16x16x32_bf16(
                    a1, bfr, acc[c4][1], 0, 0, 0);
            }
        }
        __syncthreads();
        if (ch < 3) {
#pragma unroll
            for (int j = 0; j < 32; ++j)
                lds[(cs + 8 * j) * 36 + np] = pack2(pre[j].x, pre[j].y);
            __syncthreads();
        }
    }

    float* mp = Mpart + (size_t)bid * (32 * 256);
#pragma unroll
    for (int c4 = 0; c4 < 4; ++c4)
#pragma unroll
        for (int dt = 0; dt < 2; ++dt)
#pragma unroll
            for (int r = 0; r < 4; ++r)
                mp[(dt * 16 + q * 4 + r) * 256 + (w * 4 + c4) * 16 + l15] =
                    acc[c4][dt][r];
}

// ---------------------------------------------------------------------------
// K4a: reduce 256 block-partials per batch -> Mg[b][d][c].
__global__ __launch_bounds__(256) void k4a_reduce(
    const float* __restrict__ Mpart, float* __restrict__ Mg) {
    int bid = blockIdx.x;                        // 64
    int b = bid >> 5, seg = bid & 31;
    int idx = seg * 256 + threadIdx.x;
    const float* p = Mpart + (size_t)b * 256 * 8192 + idx;
    float s0 = 0.f, s1 = 0.f, s2 = 0.f, s3 = 0.f;
    for (int j = 0; j < 256; j += 4) {
        s0 += p[(size_t)(j + 0) * 8192];
        s1 += p[(size_t)(j + 1) * 8192];
        s2 += p[(size_t)(j + 2) * 8192];
        s3 += p[(size_t)(j + 3) * 8192];
    }
    Mg[(size_t)b * 8192 + idx] = (s0 + s1) + (s2 + s3);
}

// K4b: ctxT[b][e][d] = bv[e] + rinv[b][d] * sum_c Mg[b][d][c] * Wv[e][c]
__global__ __launch_bounds__(256) void k4b_ctx(
    const float* __restrict__ Mg, const float* __restrict__ WvT,
    const float* __restrict__ bv, const float* __restrict__ rinv,
    float* __restrict__ ctxT) {
    int bid = blockIdx.x;                        // 64: b = bid>>5, d = bid&31
    int b = bid >> 5, d = bid & 31;
    int e = threadIdx.x;
    const float* mp = Mg + (size_t)b * 8192 + d * 256;   // uniform -> s_load
    float ri = rinv[b * 32 + d];
    float a0 = 0.f, a1 = 0.f, a2 = 0.f, a3 = 0.f;
    for (int c = 0; c < 256; c += 4) {
        a0 = fmaf(mp[c + 0], WvT[(size_t)(c + 0) * kC + e], a0);
        a1 = fmaf(mp[c + 1], WvT[(size_t)(c + 1) * kC + e], a1);
        a2 = fmaf(mp[c + 2], WvT[(size_t)(c + 2) * kC + e], a2);
        a3 = fmaf(mp[c + 3], WvT[(size_t)(c + 3) * kC + e], a3);
    }
    ctxT[((size_t)b * kC + e) * kCK + d] = fmaf(ri, (a0 + a1) + (a2 + a3), bv[e]);
}

// ---------------------------------------------------------------------------
// K5: out[e,n] = gamma * sum_d ctxT[e][d]*q[d,n] + x[e,n].
// Grid 2048: 512 col-groups x 4 e-chunks of 64 -> 8 blocks/CU, ~full occ.
__global__ __launch_bounds__(256) void k5_out(
    const float* __restrict__ x, const short* __restrict__ qs,
    const float* __restrict__ ctxT, const float* __restrict__ gamma,
    float* __restrict__ out) {
    int cg = blockIdx.x >> 2;                    // col-group 0..511
    int ec = blockIdx.x & 3;                     // e-chunk 0..3
    int col = cg * 256 + threadIdx.x;
    int b = col >> 16;
    int n = col & (kN - 1);
    int bu = __builtin_amdgcn_readfirstlane(b);

    const short* qp = qs + (size_t)bu * kCK * kN + n;
    float qv[kCK];
#pragma unroll
    for (int d = 0; d < kCK; ++d) qv[d] = bf2f(qp[(size_t)d * kN]);

    const int e0b = ec * 64;
    const float* cp = ctxT + (size_t)bu * kC * kCK;      // uniform -> s_load
    const float* xp = x + (size_t)bu * kC * kN + (size_t)e0b * kN + n;
    float* op = out + (size_t)bu * kC * kN + (size_t)e0b * kN + n;
    float g = gamma[0];

    for (int e0 = 0; e0 < 64; e0 += 8) {
        float xv[8];
#pragma unroll
        for (int ee = 0; ee < 8; ++ee) xv[ee] = xp[(size_t)(e0 + ee) * kN];
#pragma unroll
        for (int ee = 0; ee < 8; ++ee) {
            const float* ce = cp + (e0b + e0 + ee) * kCK;
            float a0 = 0.f, a1 = 0.f, a2 = 0.f, a3 = 0.f;
#pragma unroll
            for (int d = 0; d < kCK; d += 4) {
                a0 = fmaf(ce[d + 0], qv[d + 0], a0);
                a1 = fmaf(ce[d + 1], qv[d + 1], a1);
                a2 = fmaf(ce[d + 2], qv[d + 2], a2);
                a3 = fmaf(ce[d + 3], qv[d + 3], a3);
            }
            float att = (a0 + a1) + (a2 + a3);
            op[(size_t)(e0 + ee) * kN] = fmaf(g, att, xv[ee]);
        }
    }
}

// ---------------------------------------------------------------------------
extern "C" void kernel_launch(void* const* d_in, const int* in_sizes, int n_in,
                              void* d_out, int out_size, void* d_ws, size_t ws_size,
                              hipStream_t stream) {
    const float* x     = (const float*)d_in[0];
    const float* Wq    = (const float*)d_in[1];
    const float* bq    = (const float*)d_in[2];
    const float* Wk    = (const float*)d_in[3];
    const float* bk    = (const float*)d_in[4];
    const float* Wv    = (const float*)d_in[5];
    const float* bv    = (const float*)d_in[6];
    const float* gamma = (const float*)d_in[7];
    float* out = (float*)d_out;
    float* ws  = (float*)d_ws;

    float* klog  = ws + OFF_KLOG;
    short* qsbuf = (short*)(ws + OFF_QS);
    short* pk    = (short*)(ws + OFF_PK);
    float* wpack = ws + OFF_WPACK;
    float* biasp = ws + OFF_BIAS;
    float* WvT   = ws + OFF_WVT;
    float* pmax  = ws + OFF_PMAX;
    float* psum  = ws + OFF_PSUM;
    float* rowm  = ws + OFF_ROWM;
    float* rinv  = ws + OFF_RINV;
    float* Mg    = ws + OFF_MG;
    float* ctxT  = ws + OFF_CTXT;
    float* Mpart = ws + OFF_MPART;

    k0_prep<<<64, 256, 0, stream>>>(Wq, Wk, Wv, bq, bk,
                                    (short*)wpack, biasp, WvT);
    pa_proj<<<1024, 256, 0, stream>>>(x, wpack, biasp, klog, qsbuf, pmax, psum);
    k2_stats<<<1, 1024, 0, stream>>>(pmax, psum, rowm, rinv);
    k3_pk<<<2048, 256, 0, stream>>>(klog, rowm, pk);
    pc_M<<<512, 256, 0, stream>>>(x, pk, Mpart);
    k4a_reduce<<<64, 256, 0, stream>>>(Mpart, Mg);
    k4b_ctx<<<64, 256, 0, stream>>>(Mg, WvT, bv, rinv, ctxT);
    k5_out<<<2048, 256, 0, stream>>>(x, qsbuf, ctxT, gamma, out);
}